// Round 3
// baseline (2048.592 us; speedup 1.0000x reference)
//
#include <hip/hip_runtime.h>
#include <math.h>

#define NPTS 256
#define NB 8
#define CPL 4  // columns (and rows) per lane: 64 lanes * 4 = 256

#if __has_builtin(__builtin_amdgcn_sqrtf)
#define FSQRT __builtin_amdgcn_sqrtf
#else
#define FSQRT sqrtf
#endif

// Exact fp64 distance (contract off) for the final loss value: bit-matches
// numpy's ((d0*d0 + d1*d1) + d2*d2) then IEEE sqrt on f64-cast f32 inputs.
__device__ __forceinline__ double dist3d(double ax, double ay, double az,
                                         double bx, double by, double bz) {
#pragma clang fp contract(off)
  double d0 = ax - bx;
  double d1 = ay - by;
  double d2 = az - bz;
  double s = d0 * d0;
  s = s + d1 * d1;
  s = s + d2 * d2;
  return sqrt(s);
}

__device__ __forceinline__ float distf(float ax, float ay, float az,
                                       float bx, float by, float bz) {
  float d0 = ax - bx, d1 = ay - by, d2 = az - bz;
  return FSQRT(d0 * d0 + d1 * d1 + d2 * d2);
}

// Wave64 min-reduce of a u32 via DPP (row_shr 1/2/4/8 + row_bcast 15/31),
// result broadcast via readlane(63). Pure VALU/SALU — no LDS traffic.
__device__ __forceinline__ unsigned wave_min_u32(unsigned x) {
  unsigned r = x;
  r = min(r, (unsigned)__builtin_amdgcn_update_dpp((int)r, (int)r, 0x111, 0xF, 0xF, false));  // row_shr:1
  r = min(r, (unsigned)__builtin_amdgcn_update_dpp((int)r, (int)r, 0x112, 0xF, 0xF, false));  // row_shr:2
  r = min(r, (unsigned)__builtin_amdgcn_update_dpp((int)r, (int)r, 0x114, 0xF, 0xF, false));  // row_shr:4
  r = min(r, (unsigned)__builtin_amdgcn_update_dpp((int)r, (int)r, 0x118, 0xF, 0xF, false));  // row_shr:8
  r = min(r, (unsigned)__builtin_amdgcn_update_dpp((int)r, (int)r, 0x142, 0xF, 0xF, false));  // row_bcast:15
  r = min(r, (unsigned)__builtin_amdgcn_update_dpp((int)r, (int)r, 0x143, 0xF, 0xF, false));  // row_bcast:31
  return (unsigned)__builtin_amdgcn_readlane((int)r, 63);
}

// Uniform-index (c, owner) gather from a per-lane 4-array: 2-level cndmask
// select (c uniform) then v_readlane (owner uniform). ~15 cy, no LDS.
__device__ __forceinline__ float sel4_readlane(const float a[CPL], int c, int owner) {
  float lo = (c & 1) ? a[1] : a[0];
  float hi = (c & 1) ? a[3] : a[2];
  float s = (c & 2) ? hi : lo;
  return __int_as_float(__builtin_amdgcn_readlane(__float_as_int(s), owner));
}
__device__ __forceinline__ int sel4i_readlane(const int a[CPL], int c, int owner) {
  int lo = (c & 1) ? a[1] : a[0];
  int hi = (c & 1) ? a[3] : a[2];
  int s = (c & 2) ? hi : lo;
  return __builtin_amdgcn_readlane(s, owner);
}

// One block = one 64-lane wave per batch sample.
// JV-style LSA: column-reduction duals + greedy partial assignment, then
// shortest-augmenting-path (Dijkstra) for the remaining free rows.
// All hot row/col state lives in registers; uniform-index cross-lane reads
// use cndmask+readlane instead of LDS round-trips.
__global__ __launch_bounds__(64) void emd_lsa_kernel(
    const float* __restrict__ pred, const float* __restrict__ label,
    double* __restrict__ partial) {
  __shared__ float4 rowc[NPTS];     // {x0,x1,x2,0} row coords (read-only)
  __shared__ float ys0[NPTS], ys1[NPTS], ys2[NPTS];
  __shared__ float short_l[NPTS];   // shortest[] published for scanned cols
  __shared__ int path_l[NPTS];      // path[] published for scanned cols
  __shared__ int c4r_l[NPTS];       // col4row
  __shared__ int r4c_l[NPTS];       // row4col
  __shared__ int sr_l[NPTS];        // scanned-row flags
  __shared__ int bcfr[NPTS];        // greedy: best (lowest) col per row

  const int lane = threadIdx.x;
  const int b = blockIdx.x;
  const float* xg = pred + (size_t)b * NPTS * 3;
  const float* yg = label + (size_t)b * NPTS * 3;

  // Per-lane register state: rows lane*4+c and columns lane*4+c.
  float rx[CPL], ry[CPL], rz[CPL], ru[CPL];  // row coords + row dual u
  float yc0[CPL], yc1[CPL], yc2[CPL];        // owned columns' coords
  float v_reg[CPL];                          // column duals
  int r4c_reg[CPL];                          // mirror of r4c_l for owned cols

#pragma unroll
  for (int c = 0; c < CPL; ++c) {
    int j = lane * CPL + c;
    float x0 = xg[j * 3 + 0], x1 = xg[j * 3 + 1], x2 = xg[j * 3 + 2];
    rx[c] = x0; ry[c] = x1; rz[c] = x2; ru[c] = 0.0f;
    rowc[j] = make_float4(x0, x1, x2, 0.0f);
    float t0 = yg[j * 3 + 0], t1 = yg[j * 3 + 1], t2 = yg[j * 3 + 2];
    ys0[j] = t0; ys1[j] = t1; ys2[j] = t2;
    yc0[c] = t0; yc1[c] = t1; yc2[c] = t2;
    c4r_l[j] = -1;
    r4c_l[j] = -1;
    bcfr[j] = 0x7FFFFFFF;
  }
  __syncthreads();

  // ---- Column reduction: v[j] = min_i cost[i][j], with argmin row. ----
  float cmin[CPL];
  int imin[CPL];
#pragma unroll
  for (int c = 0; c < CPL; ++c) { cmin[c] = 3.4e38f; imin[c] = -1; }
  for (int i = 0; i < NPTS; ++i) {
    float4 rd = rowc[i];  // broadcast read; iterations independent -> pipelined
#pragma unroll
    for (int c = 0; c < CPL; ++c) {
      float d = distf(rd.x, rd.y, rd.z, yc0[c], yc1[c], yc2[c]);
      bool upd = d < cmin[c];
      cmin[c] = upd ? d : cmin[c];
      imin[c] = upd ? i : imin[c];
    }
  }
#pragma unroll
  for (int c = 0; c < CPL; ++c) {
    v_reg[c] = cmin[c];
    atomicMin(&bcfr[imin[c]], lane * CPL + c);  // LDS atomic, deterministic
  }
  __syncthreads();
  // Greedy: col j gets its argmin row iff j is the lowest col claiming it.
#pragma unroll
  for (int c = 0; c < CPL; ++c) {
    int j = lane * CPL + c;
    if (bcfr[imin[c]] == j) {
      r4c_l[j] = imin[c];
      c4r_l[imin[c]] = j;
    }
  }
  __syncthreads();
#pragma unroll
  for (int c = 0; c < CPL; ++c) r4c_reg[c] = r4c_l[lane * CPL + c];
  __syncthreads();

  const float INF = 3.4e38f;

  // ---- Shortest augmenting path for each remaining free row. ----
  for (int cur_row = 0; cur_row < NPTS; ++cur_row) {
    if (c4r_l[cur_row] != -1) continue;  // uniform

    float shortest[CPL];
    int path_r[CPL];
    int scn[CPL];
#pragma unroll
    for (int c = 0; c < CPL; ++c) {
      shortest[c] = INF;
      path_r[c] = -1;
      scn[c] = 0;
      sr_l[lane * CPL + c] = 0;
    }
    __syncthreads();

    float min_val = 0.0f;
    int i = cur_row;  // uniform (SGPR)
    int sink = -1;

    while (true) {
      sr_l[i] = 1;  // store only; read after the post-loop barrier
      // Row i's {x,y,z,u} from owner lane registers (uniform index).
      int iowner = i >> 2, ic = i & (CPL - 1);
      float xi = sel4_readlane(rx, ic, iowner);
      float yi = sel4_readlane(ry, ic, iowner);
      float zi = sel4_readlane(rz, ic, iowner);
      float ui = sel4_readlane(ru, ic, iowner);
      float base = min_val - ui;
      unsigned lkey = 0xFFFFFFFFu;
#pragma unroll
      for (int c = 0; c < CPL; ++c) {
        float cst = distf(xi, yi, zi, yc0[c], yc1[c], yc2[c]);
        float r = (base + cst) - v_reg[c];
        bool upd = (r < shortest[c]) && !scn[c];
        shortest[c] = upd ? r : shortest[c];
        path_r[c] = upd ? i : path_r[c];
        float snn = fmaxf(shortest[c], 0.0f);  // keep u32 order == f32 order
        unsigned k = (__float_as_uint(snn) & 0xFFFFFF00u) | (unsigned)(lane * CPL + c);
        k = scn[c] ? 0xFFFFFFFFu : k;
        lkey = min(lkey, k);
      }
      unsigned best = wave_min_u32(lkey);
      int jstar = (int)(best & 0xFFu);
      int csel = jstar & (CPL - 1);
      int owner = jstar >> 2;

      // Owner publishes scanned-col state (off critical path stores).
      if (owner == lane) {
        scn[csel] = 1;
        short_l[jstar] = shortest[csel];
        path_l[jstar] = path_r[csel];
      }
      // Exact min_val and next row from owner-lane registers (readlane).
      min_val = sel4_readlane(shortest, csel, owner);
      int nr = sel4i_readlane(r4c_reg, csel, owner);
      if (nr < 0) { sink = jstar; break; }
      i = nr;
    }
    __syncthreads();  // publish short_l / path_l / sr_l

    // Dual update (rows via LDS flags, cols via register state).
#pragma unroll
    for (int c = 0; c < CPL; ++c) {
      int row = lane * CPL + c;
      if (sr_l[row]) {
        float du = (row == cur_row) ? min_val : (min_val - short_l[c4r_l[row]]);
        ru[c] += du;
      }
      if (scn[c]) v_reg[c] -= min_val - shortest[c];
    }
    __syncthreads();

    if (lane == 0) {  // augment along the alternating path
      int jj = sink;
      while (true) {
        int ii = path_l[jj];
        r4c_l[jj] = ii;
        int tmp = c4r_l[ii];
        c4r_l[ii] = jj;
        jj = tmp;
        if (ii == cur_row) break;
      }
    }
    __syncthreads();
#pragma unroll
    for (int c = 0; c < CPL; ++c) r4c_reg[c] = r4c_l[lane * CPL + c];
    __syncthreads();
  }

  // ---- Final loss: exact fp64 matched distances. ----
  double s = 0.0;
#pragma unroll
  for (int c = 0; c < CPL; ++c) {
    int row = lane * CPL + c;
    int j = c4r_l[row];
    s += dist3d((double)rx[c], (double)ry[c], (double)rz[c],
                (double)ys0[j], (double)ys1[j], (double)ys2[j]);
  }
  for (int m = 1; m < 64; m <<= 1) s += __shfl_xor(s, m);
  if (lane == 0) partial[b] = s;
}

__global__ void emd_finalize_kernel(const double* __restrict__ partial,
                                    float* __restrict__ out) {
  if (threadIdx.x == 0 && blockIdx.x == 0) {
    double s = 0.0;
    for (int b = 0; b < NB; ++b) s += partial[b];
    out[0] = (float)(s / (double)(NB * NPTS));
  }
}

extern "C" void kernel_launch(void* const* d_in, const int* in_sizes, int n_in,
                              void* d_out, int out_size, void* d_ws, size_t ws_size,
                              hipStream_t stream) {
  const float* pred = (const float*)d_in[0];
  const float* label = (const float*)d_in[1];
  double* partial = (double*)d_ws;  // 8 doubles
  emd_lsa_kernel<<<NB, 64, 0, stream>>>(pred, label, partial);
  emd_finalize_kernel<<<1, 64, 0, stream>>>(partial, (float*)d_out);
}